// Round 1
// 1312.141 us; speedup vs baseline: 1.0679x; 1.0679x over previous
//
#include <hip/hip_runtime.h>
#include <stdint.h>

// BitLinear forward on MI355X:
//   C[m,n] = (s_m * wscale) * sum_k q[m,k] * t[n,k]
//   q in int8 [-8,7] (per-token int4 quant), t in {-1,0,1} (ternary weights)
// Exact int32 accumulation via v_mfma_i32_16x16x64_i8.
//
// M = 4*2048 = 8192, N = 16384, K = 4096.
//
// GEMM: 256x256 tile, 8 waves (2Mx4N), BK=64, ring-4 LDS double-buffer
// (128 KiB), phased schedule with counted vmcnt (never 0 in main loop),
// raw s_barrier + s_setprio around MFMA clusters (T3+T4+T5 per the
// 256^2 8-phase template). Ring-4 staging: tile t read from buf[t&3],
// tile t+2 staged into buf[(t+2)&3] -> staging target was last read 2
// iterations (>=4 barriers) ago: race-free by construction.

#define K_DIM 4096
#define M_DIM 8192
#define N_DIM 16384

typedef int v4i __attribute__((ext_vector_type(4)));

typedef __attribute__((address_space(1))) void gvoid_t;
typedef __attribute__((address_space(3))) void lvoid_t;

__device__ __forceinline__ void gl_lds16(const void* g, void* l) {
    // async global->LDS, 16B per lane; LDS dest is wave-uniform base + lane*16
    __builtin_amdgcn_global_load_lds((gvoid_t*)(void*)g, (lvoid_t*)l, 16, 0, 0);
}

// ---------------- Phase 1a: partial sums of |w| ----------------
__global__ __launch_bounds__(256) void wabs_partial_k(const float* __restrict__ w,
                                                      double* __restrict__ part) {
    const long n4 = (long)N_DIM * K_DIM / 4;  // 16,777,216 float4s
    long i = (long)blockIdx.x * blockDim.x + threadIdx.x;
    const long stride = (long)gridDim.x * blockDim.x;
    const float4* w4 = (const float4*)w;
    double s = 0.0;
    for (; i < n4; i += stride) {
        float4 v = w4[i];
        s += (double)fabsf(v.x);
        s += (double)fabsf(v.y);
        s += (double)fabsf(v.z);
        s += (double)fabsf(v.w);
    }
    __shared__ double red[256];
    const int tid = threadIdx.x;
    red[tid] = s;
    __syncthreads();
    for (int w2 = 128; w2 > 0; w2 >>= 1) {
        if (tid < w2) red[tid] += red[tid + w2];
        __syncthreads();
    }
    if (tid == 0) part[blockIdx.x] = red[0];
}

// ---------------- Phase 1b: final mean -> wscale ----------------
__global__ __launch_bounds__(256) void wscale_final_k(const double* __restrict__ part,
                                                      float* __restrict__ wscale) {
    __shared__ double red[256];
    const int tid = threadIdx.x;
    double s = 0.0;
    for (int i = tid; i < 1024; i += 256) s += part[i];
    red[tid] = s;
    __syncthreads();
    for (int w2 = 128; w2 > 0; w2 >>= 1) {
        if (tid < w2) red[tid] += red[tid + w2];
        __syncthreads();
    }
    if (tid == 0) {
        double mean = red[0] / (double)((long)N_DIM * K_DIM);
        *wscale = fmaxf((float)mean, 1e-5f);
    }
}

// ---------------- Phase 2: ternary-quantize weights ----------------
// Strictly coalesced: 16 B/lane float4 reads, 4 B/lane packed writes.
__global__ __launch_bounds__(256) void wquant_k(const float* __restrict__ w,
                                                signed char* __restrict__ qw,
                                                const float* __restrict__ wscale) {
    const float sc = *wscale;
    const long n4 = (long)N_DIM * K_DIM / 4;  // 16,777,216
    long i = (long)blockIdx.x * blockDim.x + threadIdx.x;
    const long stride = (long)gridDim.x * blockDim.x;
    const float4* w4 = (const float4*)w;
    int* q4 = (int*)qw;
    for (; i < n4; i += stride) {
        float4 v = w4[i];
        union { signed char c[4]; int u; } p;
        p.c[0] = (signed char)fminf(fmaxf(rintf(v.x / sc), -1.f), 1.f);
        p.c[1] = (signed char)fminf(fmaxf(rintf(v.y / sc), -1.f), 1.f);
        p.c[2] = (signed char)fminf(fmaxf(rintf(v.z / sc), -1.f), 1.f);
        p.c[3] = (signed char)fminf(fmaxf(rintf(v.w / sc), -1.f), 1.f);
        q4[i] = p.u;
    }
}

// ---------------- Phase 3: per-token absmax quant of x ----------------
// One block per row; 16 B/lane reads at stride 256 float4s, 4 B/lane writes.
__global__ __launch_bounds__(256) void xquant_k(const float* __restrict__ x,
                                                signed char* __restrict__ qx,
                                                float* __restrict__ sx,
                                                const float* __restrict__ wscale) {
    const int row = blockIdx.x;       // 0..8191
    const int tid = threadIdx.x;
    const float4* xr = (const float4*)(x + (long)row * K_DIM);
    float4 v[4];
    float am = 0.f;
#pragma unroll
    for (int j = 0; j < 4; ++j) {
        v[j] = xr[tid + j * 256];
        am = fmaxf(am, fmaxf(fmaxf(fabsf(v[j].x), fabsf(v[j].y)),
                             fmaxf(fabsf(v[j].z), fabsf(v[j].w))));
    }
#pragma unroll
    for (int off = 32; off > 0; off >>= 1) am = fmaxf(am, __shfl_down(am, off));
    __shared__ float wm[4];
    if ((tid & 63) == 0) wm[tid >> 6] = am;
    __syncthreads();
    am = fmaxf(fmaxf(wm[0], wm[1]), fmaxf(wm[2], wm[3]));
    const float s = fmaxf(am, 1e-5f) / 7.0f;   // identical fp32 ops to reference
    int* qr = (int*)(qx + (long)row * K_DIM);
#pragma unroll
    for (int j = 0; j < 4; ++j) {
        union { signed char c[4]; int u; } p;
        p.c[0] = (signed char)fminf(fmaxf(rintf(v[j].x / s), -8.f), 7.f);
        p.c[1] = (signed char)fminf(fmaxf(rintf(v[j].y / s), -8.f), 7.f);
        p.c[2] = (signed char)fminf(fmaxf(rintf(v[j].z / s), -8.f), 7.f);
        p.c[3] = (signed char)fminf(fmaxf(rintf(v[j].w / s), -8.f), 7.f);
        qr[tid + j * 256] = p.u;
    }
    if (tid == 0) sx[row] = s * (*wscale);     // fused output scale
}

// ---------------- Phase 4: int8 GEMM (256x256 tile, BK=64, ring-4) ----------
// A = qx (MxK row-major), B = qw (NxK row-major, i.e. B^T GEMM).
// 8 waves (2Mx4N), each computes 128x64 via 8x4 grid of 16x16x64 i8 MFMAs.
// LDS chunk swizzle (measured zero-conflict): chunk (row r, kgroup q) at byte
// offset r*64 + ((q+(r>>1))&3)*16; inverse applied on the global source so
// global_load_lds stays lane-linear.
__global__ __launch_bounds__(512) void gemm_k(const signed char* __restrict__ qx,
                                              const signed char* __restrict__ qw,
                                              const float* __restrict__ sx,
                                              float* __restrict__ out) {
    // ring of 4 buffers: [A 16 KB | B 16 KB] each
    __shared__ __align__(16) signed char lds[4][32768];

    const int tid  = threadIdx.x;
    const int lane = tid & 63;
    const int wave = tid >> 6;
    const int wm = wave >> 2;          // 0..1
    const int wn = wave & 3;           // 0..3

    // XCD-aware mapping: grid = 2048 linear (2048 % 8 == 0 -> bijective).
    // Each XCD owns an 8-wide nt strip; inside, nt-pairs x mt snake keeps
    // working set ~3 MB (2 B-panels + 1 A-panel) per L2.
    const int bid = blockIdx.x;
    const int xcd = bid & 7;
    const int cid = bid >> 3;                           // 0..255
    const int mt  = (cid >> 1) & 31;                    // 32 m-tiles
    const int nt  = (xcd << 3) + ((cid >> 6) << 1) + (cid & 1);  // 64 n-tiles
    const int m0 = mt << 8;
    const int n0 = nt << 8;

    // ---- staging addresses (thread stages chunks {tid, tid+512} of A and B) --
    // chunk c: row r = c>>2, lds slot = c&3, global kgroup g = ((c&3)-((r>>1)&3))&3
    // c1 = tid+512 has the same (c&3) and ((r>>1)&3) -> same g, row +128.
    const int r = tid >> 2;                              // 0..127
    const int g = ((tid & 3) - ((tid >> 3) & 3)) & 3;    // inverse swizzle
    const signed char* gA = qx + (long)(m0 + r) * K_DIM + (g << 4);
    const signed char* gB = qw + (long)(n0 + r) * K_DIM + (g << 4);
    const int oSA0 = tid << 4;
    const int oSA1 = (tid << 4) + 8192;
    const int oSB0 = (tid << 4) + 16384;
    const int oSB1 = (tid << 4) + 24576;

    // ---- fragment read offsets: A[m=lane&15][k=(lane>>4)*16+j] ----
    const int fr = lane & 15;
    const int fq = lane >> 4;
    int offA[8], offB[4];
#pragma unroll
    for (int i = 0; i < 8; ++i) {
        const int ra = wm * 128 + i * 16 + fr;
        offA[i] = ra * 64 + (((fq + (ra >> 1)) & 3) << 4);
    }
#pragma unroll
    for (int j = 0; j < 4; ++j) {
        const int rb = wn * 64 + j * 16 + fr;
        offB[j] = 16384 + rb * 64 + (((fq + (rb >> 1)) & 3) << 4);
    }

    v4i acc[8][4];
#pragma unroll
    for (int i = 0; i < 8; ++i)
#pragma unroll
        for (int j = 0; j < 4; ++j) acc[i][j] = 0;

    // ---- prologue: stage tile 0 -> buf0, tile 1 -> buf1 (issue order matters:
    // vmcnt counting groups 4 loads per tile) ----
    gl_lds16(gA,                      &lds[0][oSA0]);
    gl_lds16(gA + 128 * K_DIM,        &lds[0][oSA1]);
    gl_lds16(gB,                      &lds[0][oSB0]);
    gl_lds16(gB + 128 * K_DIM,        &lds[0][oSB1]);
    gl_lds16(gA + 64,                 &lds[1][oSA0]);
    gl_lds16(gA + 128 * K_DIM + 64,   &lds[1][oSA1]);
    gl_lds16(gB + 64,                 &lds[1][oSB0]);
    gl_lds16(gB + 128 * K_DIM + 64,   &lds[1][oSB1]);

    // ---- main loop: 64 K-tiles, 2 phases each ----
    for (int t = 0; t < 64; ++t) {
        // counted wait: newest 4 outstanding loads are tile t+1's; all older
        // (i.e. tile t's) have landed. Barrier publishes across waves.
        if (t == 63) { asm volatile("s_waitcnt vmcnt(0)" ::: "memory"); }
        else         { asm volatile("s_waitcnt vmcnt(4)" ::: "memory"); }
        __builtin_amdgcn_s_barrier();

        const signed char* cur = lds[t & 3];
        signed char* nb = lds[(t + 2) & 3];
        const long k2 = (long)(t + 2) << 6;
        const bool st = (t < 62);

        v4i a[4], b[4];

        // ---- phase 0: B frags + A frags 0-3, stage A half-tiles of t+2 ----
#pragma unroll
        for (int j = 0; j < 4; ++j) b[j] = *(const v4i*)(cur + offB[j]);
#pragma unroll
        for (int i = 0; i < 4; ++i) a[i] = *(const v4i*)(cur + offA[i]);
        if (st) {
            gl_lds16(gA + k2,                 nb + oSA0);
            gl_lds16(gA + 128 * K_DIM + k2,   nb + oSA1);
        }
        __builtin_amdgcn_s_barrier();
        __builtin_amdgcn_s_setprio(1);
#pragma unroll
        for (int i = 0; i < 4; ++i)
#pragma unroll
            for (int j = 0; j < 4; ++j)
                acc[i][j] = __builtin_amdgcn_mfma_i32_16x16x64_i8(a[i], b[j], acc[i][j], 0, 0, 0);
        __builtin_amdgcn_s_setprio(0);
        __builtin_amdgcn_s_barrier();

        // ---- phase 1: A frags 4-7, stage B half-tiles of t+2 ----
#pragma unroll
        for (int i = 0; i < 4; ++i) a[i] = *(const v4i*)(cur + offA[4 + i]);
        if (st) {
            gl_lds16(gB + k2,                 nb + oSB0);
            gl_lds16(gB + 128 * K_DIM + k2,   nb + oSB1);
        }
        __builtin_amdgcn_s_barrier();
        __builtin_amdgcn_s_setprio(1);
#pragma unroll
        for (int i = 0; i < 4; ++i)
#pragma unroll
            for (int j = 0; j < 4; ++j)
                acc[4 + i][j] = __builtin_amdgcn_mfma_i32_16x16x64_i8(a[i], b[j], acc[4 + i][j], 0, 0, 0);
        __builtin_amdgcn_s_setprio(0);
        // no trailing barrier: next iteration's vmcnt+barrier closes the phase
    }

    // ---- epilogue: C/D layout col=lane&15, row=(lane>>4)*4+reg ----
#pragma unroll
    for (int i = 0; i < 8; ++i) {
        const int mrow = m0 + wm * 128 + i * 16 + fq * 4;
#pragma unroll
        for (int rr = 0; rr < 4; ++rr) {
            const int m = mrow + rr;
            const float sm = sx[m];
            float* orow = out + (long)m * N_DIM + n0 + wn * 64 + fr;
#pragma unroll
            for (int j = 0; j < 4; ++j)
                orow[j * 16] = (float)acc[i][j][rr] * sm;
        }
    }
}

extern "C" void kernel_launch(void* const* d_in, const int* in_sizes, int n_in,
                              void* d_out, int out_size, void* d_ws, size_t ws_size,
                              hipStream_t stream) {
    const float* x = (const float*)d_in[0];        // (4,2048,4096) fp32
    const float* w = (const float*)d_in[1];        // (16384,4096) fp32
    float* out = (float*)d_out;                    // (4,2048,16384) fp32
    char* ws = (char*)d_ws;

    // workspace layout (~100.7 MB total)
    double* part         = (double*)(ws);                        // 8 KB
    float*  wscale       = (float*)(ws + 8192);                  // 4 B
    float*  sx           = (float*)(ws + 16384);                 // 32 KB
    signed char* qx      = (signed char*)(ws + 65536);                    // 32 MB
    signed char* qw      = (signed char*)(ws + 65536 + (size_t)33554432); // 64 MB

    wabs_partial_k<<<1024, 256, 0, stream>>>(w, part);
    wscale_final_k<<<1, 256, 0, stream>>>(part, wscale);
    wquant_k<<<2048, 256, 0, stream>>>(w, qw, wscale);
    xquant_k<<<8192, 256, 0, stream>>>(x, qx, sx, wscale);
    gemm_k<<<2048, 512, 0, stream>>>(qx, qw, sx, out);
}

// Round 2
// 1277.583 us; speedup vs baseline: 1.0968x; 1.0270x over previous
//
#include <hip/hip_runtime.h>
#include <stdint.h>

// BitLinear forward on MI355X:
//   C[m,n] = (s_m * wscale) * sum_k q[m,k] * t[n,k]
//   q in int8 [-8,7] (per-token int4 quant), t in {-1,0,1} (ternary weights)
// Exact int32 accumulation via v_mfma_i32_16x16x64_i8.
//
// M = 4*2048 = 8192, N = 16384, K = 4096.
//
// GEMM: 256x256 tile, 8 waves (2Mx4N), BK=64, ring-4 LDS buffers (128 KiB),
// ONE counted-vmcnt + s_barrier per K-tile (never vmcnt(0) in main loop).
// Ring-4 safety: staging in iter t targets buf[(t+2)&3], last read in iter
// t-2; any wave past barrier(t) has completed body(t-1) (its ds_reads are
// lgkmcnt-drained by its own MFMAs before the barrier), so the target is
// free. Single sync point per tile lets waves skew -> LDS pipe overlaps
// matrix pipe across waves (round-1's 4-barrier lockstep serialized them).

#define K_DIM 4096
#define M_DIM 8192
#define N_DIM 16384

typedef int v4i __attribute__((ext_vector_type(4)));

typedef __attribute__((address_space(1))) void gvoid_t;
typedef __attribute__((address_space(3))) void lvoid_t;

__device__ __forceinline__ void gl_lds16(const void* g, void* l) {
    // async global->LDS, 16B per lane; LDS dest is wave-uniform base + lane*16
    __builtin_amdgcn_global_load_lds((gvoid_t*)(void*)g, (lvoid_t*)l, 16, 0, 0);
}

// ---------------- Phase 1a: partial sums of |w| ----------------
__global__ __launch_bounds__(256) void wabs_partial_k(const float* __restrict__ w,
                                                      double* __restrict__ part) {
    const long n4 = (long)N_DIM * K_DIM / 4;  // 16,777,216 float4s
    long i = (long)blockIdx.x * blockDim.x + threadIdx.x;
    const long stride = (long)gridDim.x * blockDim.x;
    const float4* w4 = (const float4*)w;
    double s = 0.0;
    for (; i < n4; i += stride) {
        float4 v = w4[i];
        s += (double)fabsf(v.x);
        s += (double)fabsf(v.y);
        s += (double)fabsf(v.z);
        s += (double)fabsf(v.w);
    }
    __shared__ double red[256];
    const int tid = threadIdx.x;
    red[tid] = s;
    __syncthreads();
    for (int w2 = 128; w2 > 0; w2 >>= 1) {
        if (tid < w2) red[tid] += red[tid + w2];
        __syncthreads();
    }
    if (tid == 0) part[blockIdx.x] = red[0];
}

// ---------------- Phase 1b: final mean -> wscale ----------------
__global__ __launch_bounds__(256) void wscale_final_k(const double* __restrict__ part,
                                                      float* __restrict__ wscale) {
    __shared__ double red[256];
    const int tid = threadIdx.x;
    double s = 0.0;
    for (int i = tid; i < 1024; i += 256) s += part[i];
    red[tid] = s;
    __syncthreads();
    for (int w2 = 128; w2 > 0; w2 >>= 1) {
        if (tid < w2) red[tid] += red[tid + w2];
        __syncthreads();
    }
    if (tid == 0) {
        double mean = red[0] / (double)((long)N_DIM * K_DIM);
        *wscale = fmaxf((float)mean, 1e-5f);
    }
}

// ---------------- Phase 2: ternary-quantize weights ----------------
// Strictly coalesced: 16 B/lane float4 reads, 4 B/lane packed writes.
__global__ __launch_bounds__(256) void wquant_k(const float* __restrict__ w,
                                                signed char* __restrict__ qw,
                                                const float* __restrict__ wscale) {
    const float sc = *wscale;
    const long n4 = (long)N_DIM * K_DIM / 4;  // 16,777,216
    long i = (long)blockIdx.x * blockDim.x + threadIdx.x;
    const long stride = (long)gridDim.x * blockDim.x;
    const float4* w4 = (const float4*)w;
    int* q4 = (int*)qw;
    for (; i < n4; i += stride) {
        float4 v = w4[i];
        union { signed char c[4]; int u; } p;
        p.c[0] = (signed char)fminf(fmaxf(rintf(v.x / sc), -1.f), 1.f);
        p.c[1] = (signed char)fminf(fmaxf(rintf(v.y / sc), -1.f), 1.f);
        p.c[2] = (signed char)fminf(fmaxf(rintf(v.z / sc), -1.f), 1.f);
        p.c[3] = (signed char)fminf(fmaxf(rintf(v.w / sc), -1.f), 1.f);
        q4[i] = p.u;
    }
}

// ---------------- Phase 3: per-token absmax quant of x ----------------
// One block per row; 16 B/lane reads at stride 256 float4s, 4 B/lane writes.
__global__ __launch_bounds__(256) void xquant_k(const float* __restrict__ x,
                                                signed char* __restrict__ qx,
                                                float* __restrict__ sx,
                                                const float* __restrict__ wscale) {
    const int row = blockIdx.x;       // 0..8191
    const int tid = threadIdx.x;
    const float4* xr = (const float4*)(x + (long)row * K_DIM);
    float4 v[4];
    float am = 0.f;
#pragma unroll
    for (int j = 0; j < 4; ++j) {
        v[j] = xr[tid + j * 256];
        am = fmaxf(am, fmaxf(fmaxf(fabsf(v[j].x), fabsf(v[j].y)),
                             fmaxf(fabsf(v[j].z), fabsf(v[j].w))));
    }
#pragma unroll
    for (int off = 32; off > 0; off >>= 1) am = fmaxf(am, __shfl_down(am, off));
    __shared__ float wm[4];
    if ((tid & 63) == 0) wm[tid >> 6] = am;
    __syncthreads();
    am = fmaxf(fmaxf(wm[0], wm[1]), fmaxf(wm[2], wm[3]));
    const float s = fmaxf(am, 1e-5f) / 7.0f;   // identical fp32 ops to reference
    int* qr = (int*)(qx + (long)row * K_DIM);
#pragma unroll
    for (int j = 0; j < 4; ++j) {
        union { signed char c[4]; int u; } p;
        p.c[0] = (signed char)fminf(fmaxf(rintf(v[j].x / s), -8.f), 7.f);
        p.c[1] = (signed char)fminf(fmaxf(rintf(v[j].y / s), -8.f), 7.f);
        p.c[2] = (signed char)fminf(fmaxf(rintf(v[j].z / s), -8.f), 7.f);
        p.c[3] = (signed char)fminf(fmaxf(rintf(v[j].w / s), -8.f), 7.f);
        qr[tid + j * 256] = p.u;
    }
    if (tid == 0) sx[row] = s * (*wscale);     // fused output scale
}

// ---------------- Phase 4: int8 GEMM (256x256 tile, BK=64, ring-4) ----------
// A = qx (MxK row-major), B = qw (NxK row-major, i.e. B^T GEMM).
// 8 waves (2Mx4N), each computes 128x64 via 8x4 grid of 16x16x64 i8 MFMAs.
// LDS chunk swizzle (measured zero-conflict): chunk (row r, kgroup q) at byte
// offset r*64 + ((q+(r>>1))&3)*16; inverse applied on the global source so
// global_load_lds stays lane-linear.
__global__ __launch_bounds__(512, 2) void gemm_k(const signed char* __restrict__ qx,
                                                 const signed char* __restrict__ qw,
                                                 const float* __restrict__ sx,
                                                 float* __restrict__ out) {
    // ring of 4 buffers: [A 16 KB | B 16 KB] each
    __shared__ __align__(16) signed char lds[4][32768];

    const int tid  = threadIdx.x;
    const int lane = tid & 63;
    const int wave = tid >> 6;
    const int wm = wave >> 2;          // 0..1
    const int wn = wave & 3;           // 0..3

    // XCD-aware mapping: grid = 2048 linear (2048 % 8 == 0 -> bijective).
    const int bid = blockIdx.x;
    const int xcd = bid & 7;
    const int cid = bid >> 3;                           // 0..255
    const int mt  = (cid >> 1) & 31;                    // 32 m-tiles
    const int nt  = (xcd << 3) + ((cid >> 6) << 1) + (cid & 1);  // 64 n-tiles
    const int m0 = mt << 8;
    const int n0 = nt << 8;

    // ---- staging addresses (thread stages chunks {tid, tid+512} of A and B) --
    // chunk c: row r = c>>2, lds slot = c&3, global kgroup g = ((c&3)-((r>>1)&3))&3
    // c1 = tid+512 has the same (c&3) and ((r>>1)&3) -> same g, row +128.
    const int r = tid >> 2;                              // 0..127
    const int g = ((tid & 3) - ((tid >> 3) & 3)) & 3;    // inverse swizzle
    const signed char* gA = qx + (long)(m0 + r) * K_DIM + (g << 4);
    const signed char* gB = qw + (long)(n0 + r) * K_DIM + (g << 4);
    const int oSA0 = tid << 4;
    const int oSA1 = (tid << 4) + 8192;
    const int oSB0 = (tid << 4) + 16384;
    const int oSB1 = (tid << 4) + 24576;

    // ---- fragment read offsets: A[m=lane&15][k=(lane>>4)*16+j] ----
    const int fr = lane & 15;
    const int fq = lane >> 4;
    int offA[8], offB[4];
#pragma unroll
    for (int i = 0; i < 8; ++i) {
        const int ra = wm * 128 + i * 16 + fr;
        offA[i] = ra * 64 + (((fq + (ra >> 1)) & 3) << 4);
    }
#pragma unroll
    for (int j = 0; j < 4; ++j) {
        const int rb = wn * 64 + j * 16 + fr;
        offB[j] = 16384 + rb * 64 + (((fq + (rb >> 1)) & 3) << 4);
    }

    v4i acc[8][4];
#pragma unroll
    for (int i = 0; i < 8; ++i)
#pragma unroll
        for (int j = 0; j < 4; ++j) acc[i][j] = 0;

    // ---- prologue: stage tile 0 -> buf0, tile 1 -> buf1 (4 loads per tile,
    // issue order defines vmcnt groups) ----
    gl_lds16(gA,                      &lds[0][oSA0]);
    gl_lds16(gA + 128 * K_DIM,        &lds[0][oSA1]);
    gl_lds16(gB,                      &lds[0][oSB0]);
    gl_lds16(gB + 128 * K_DIM,        &lds[0][oSB1]);
    gl_lds16(gA + 64,                 &lds[1][oSA0]);
    gl_lds16(gA + 128 * K_DIM + 64,   &lds[1][oSA1]);
    gl_lds16(gB + 64,                 &lds[1][oSB0]);
    gl_lds16(gB + 128 * K_DIM + 64,   &lds[1][oSB1]);

    // ---- main loop: 64 K-tiles, ONE sync point each ----
    for (int t = 0; t < 64; ++t) {
        // counted wait: newest 4 outstanding loads are tile t+1's; everything
        // older (tile t's) has landed. Each wave waits its own vmcnt BEFORE
        // the barrier, so after the barrier all waves' tile-t data is in LDS.
        if (t == 63) { asm volatile("s_waitcnt vmcnt(0)" ::: "memory"); }
        else         { asm volatile("s_waitcnt vmcnt(4)" ::: "memory"); }
        __builtin_amdgcn_s_barrier();

        const signed char* cur = lds[t & 3];
        signed char* nb = (signed char*)lds[(t + 2) & 3];

        // issue next-next tile's staging first: loads in flight earliest
        if (t < 62) {
            const long k2 = (long)(t + 2) << 6;
            gl_lds16(gA + k2,                 nb + oSA0);
            gl_lds16(gA + 128 * K_DIM + k2,   nb + oSA1);
            gl_lds16(gB + k2,                 nb + oSB0);
            gl_lds16(gB + 128 * K_DIM + k2,   nb + oSB1);
        }

        // all 12 fragment reads into distinct registers (no false deps);
        // compiler interleaves lgkmcnt so MFMAs start as operands land.
        v4i a[8], b[4];
#pragma unroll
        for (int j = 0; j < 4; ++j) b[j] = *(const v4i*)(cur + offB[j]);
#pragma unroll
        for (int i = 0; i < 8; ++i) a[i] = *(const v4i*)(cur + offA[i]);

        __builtin_amdgcn_s_setprio(1);
#pragma unroll
        for (int i = 0; i < 8; ++i)
#pragma unroll
            for (int j = 0; j < 4; ++j)
                acc[i][j] = __builtin_amdgcn_mfma_i32_16x16x64_i8(a[i], b[j], acc[i][j], 0, 0, 0);
        __builtin_amdgcn_s_setprio(0);
    }

    // ---- epilogue: C/D layout col=lane&15, row=(lane>>4)*4+reg ----
#pragma unroll
    for (int i = 0; i < 8; ++i) {
        const int mrow = m0 + wm * 128 + i * 16 + fq * 4;
#pragma unroll
        for (int rr = 0; rr < 4; ++rr) {
            const int m = mrow + rr;
            const float sm = sx[m];
            float* orow = out + (long)m * N_DIM + n0 + wn * 64 + fr;
#pragma unroll
            for (int j = 0; j < 4; ++j)
                orow[j * 16] = (float)acc[i][j][rr] * sm;
        }
    }
}

extern "C" void kernel_launch(void* const* d_in, const int* in_sizes, int n_in,
                              void* d_out, int out_size, void* d_ws, size_t ws_size,
                              hipStream_t stream) {
    const float* x = (const float*)d_in[0];        // (4,2048,4096) fp32
    const float* w = (const float*)d_in[1];        // (16384,4096) fp32
    float* out = (float*)d_out;                    // (4,2048,16384) fp32
    char* ws = (char*)d_ws;

    // workspace layout (~100.7 MB total)
    double* part         = (double*)(ws);                        // 8 KB
    float*  wscale       = (float*)(ws + 8192);                  // 4 B
    float*  sx           = (float*)(ws + 16384);                 // 32 KB
    signed char* qx      = (signed char*)(ws + 65536);                    // 32 MB
    signed char* qw      = (signed char*)(ws + 65536 + (size_t)33554432); // 64 MB

    wabs_partial_k<<<1024, 256, 0, stream>>>(w, part);
    wscale_final_k<<<1, 256, 0, stream>>>(part, wscale);
    wquant_k<<<2048, 256, 0, stream>>>(w, qw, wscale);
    xquant_k<<<8192, 256, 0, stream>>>(x, qx, sx, wscale);
    gemm_k<<<2048, 512, 0, stream>>>(qx, qw, sx, out);
}

// Round 3
// 1276.246 us; speedup vs baseline: 1.0980x; 1.0010x over previous
//
#include <hip/hip_runtime.h>
#include <stdint.h>

// BitLinear forward on MI355X:
//   C[m,n] = (s_m * wscale) * sum_k q[m,k] * t[n,k]
//   q in int8 [-8,7] (per-token int4 quant), t in {-1,0,1} (ternary weights)
// Exact int32 accumulation via v_mfma_i32_16x16x64_i8.
//
// M = 4*2048 = 8192, N = 16384, K = 4096.
//
// GEMM: 256x256 tile, 8 waves (2Mx4N), BK=64, ring-4 LDS buffers (128 KiB),
// REGISTER-DOUBLE-BUFFERED fragments: iter t computes MFMA(t) from regs
// loaded during iter t-1 while issuing ds_reads for tile t+1 into the
// alternate reg set -> MFMA has no in-body lgkmcnt dependency; ~1150 cyc
// of LDS traffic hides under ~1300 cyc of MFMA.
// Staging distance 3: iter t stages buf[(t+3)&3] = buf[(t-1)&3]; tile t-1's
// frag reads were lgkmcnt-drained by MFMA(t-1) before barrier(t) -> free.
// Counted vmcnt(4) (never 0 until drain): at top of iter t the newest 4
// outstanding loads are tile t+2's, so tile t+1 has landed -> its frags are
// readable right after the barrier.

#define K_DIM 4096
#define M_DIM 8192
#define N_DIM 16384

typedef int v4i __attribute__((ext_vector_type(4)));

typedef __attribute__((address_space(1))) void gvoid_t;
typedef __attribute__((address_space(3))) void lvoid_t;

__device__ __forceinline__ void gl_lds16(const void* g, void* l) {
    // async global->LDS, 16B per lane; LDS dest is wave-uniform base + lane*16
    __builtin_amdgcn_global_load_lds((gvoid_t*)(void*)g, (lvoid_t*)l, 16, 0, 0);
}

// ---------------- Phase 1a: partial sums of |w| ----------------
__global__ __launch_bounds__(256) void wabs_partial_k(const float* __restrict__ w,
                                                      double* __restrict__ part) {
    const long n4 = (long)N_DIM * K_DIM / 4;  // 16,777,216 float4s
    long i = (long)blockIdx.x * blockDim.x + threadIdx.x;
    const long stride = (long)gridDim.x * blockDim.x;
    const float4* w4 = (const float4*)w;
    double s = 0.0;
    for (; i < n4; i += stride) {
        float4 v = w4[i];
        s += (double)fabsf(v.x);
        s += (double)fabsf(v.y);
        s += (double)fabsf(v.z);
        s += (double)fabsf(v.w);
    }
    __shared__ double red[256];
    const int tid = threadIdx.x;
    red[tid] = s;
    __syncthreads();
    for (int w2 = 128; w2 > 0; w2 >>= 1) {
        if (tid < w2) red[tid] += red[tid + w2];
        __syncthreads();
    }
    if (tid == 0) part[blockIdx.x] = red[0];
}

// ---------------- Phase 1b: final mean -> wscale ----------------
__global__ __launch_bounds__(256) void wscale_final_k(const double* __restrict__ part,
                                                      float* __restrict__ wscale) {
    __shared__ double red[256];
    const int tid = threadIdx.x;
    double s = 0.0;
    for (int i = tid; i < 1024; i += 256) s += part[i];
    red[tid] = s;
    __syncthreads();
    for (int w2 = 128; w2 > 0; w2 >>= 1) {
        if (tid < w2) red[tid] += red[tid + w2];
        __syncthreads();
    }
    if (tid == 0) {
        double mean = red[0] / (double)((long)N_DIM * K_DIM);
        *wscale = fmaxf((float)mean, 1e-5f);
    }
}

// ---------------- Phase 2: ternary-quantize weights ----------------
// Strictly coalesced: 16 B/lane float4 reads, 4 B/lane packed writes.
__global__ __launch_bounds__(256) void wquant_k(const float* __restrict__ w,
                                                signed char* __restrict__ qw,
                                                const float* __restrict__ wscale) {
    const float sc = *wscale;
    const long n4 = (long)N_DIM * K_DIM / 4;  // 16,777,216
    long i = (long)blockIdx.x * blockDim.x + threadIdx.x;
    const long stride = (long)gridDim.x * blockDim.x;
    const float4* w4 = (const float4*)w;
    int* q4 = (int*)qw;
    for (; i < n4; i += stride) {
        float4 v = w4[i];
        union { signed char c[4]; int u; } p;
        p.c[0] = (signed char)fminf(fmaxf(rintf(v.x / sc), -1.f), 1.f);
        p.c[1] = (signed char)fminf(fmaxf(rintf(v.y / sc), -1.f), 1.f);
        p.c[2] = (signed char)fminf(fmaxf(rintf(v.z / sc), -1.f), 1.f);
        p.c[3] = (signed char)fminf(fmaxf(rintf(v.w / sc), -1.f), 1.f);
        q4[i] = p.u;
    }
}

// ---------------- Phase 3: per-token absmax quant of x ----------------
// One block per row; 16 B/lane reads at stride 256 float4s, 4 B/lane writes.
__global__ __launch_bounds__(256) void xquant_k(const float* __restrict__ x,
                                                signed char* __restrict__ qx,
                                                float* __restrict__ sx,
                                                const float* __restrict__ wscale) {
    const int row = blockIdx.x;       // 0..8191
    const int tid = threadIdx.x;
    const float4* xr = (const float4*)(x + (long)row * K_DIM);
    float4 v[4];
    float am = 0.f;
#pragma unroll
    for (int j = 0; j < 4; ++j) {
        v[j] = xr[tid + j * 256];
        am = fmaxf(am, fmaxf(fmaxf(fabsf(v[j].x), fabsf(v[j].y)),
                             fmaxf(fabsf(v[j].z), fabsf(v[j].w))));
    }
#pragma unroll
    for (int off = 32; off > 0; off >>= 1) am = fmaxf(am, __shfl_down(am, off));
    __shared__ float wm[4];
    if ((tid & 63) == 0) wm[tid >> 6] = am;
    __syncthreads();
    am = fmaxf(fmaxf(wm[0], wm[1]), fmaxf(wm[2], wm[3]));
    const float s = fmaxf(am, 1e-5f) / 7.0f;   // identical fp32 ops to reference
    int* qr = (int*)(qx + (long)row * K_DIM);
#pragma unroll
    for (int j = 0; j < 4; ++j) {
        union { signed char c[4]; int u; } p;
        p.c[0] = (signed char)fminf(fmaxf(rintf(v[j].x / s), -8.f), 7.f);
        p.c[1] = (signed char)fminf(fmaxf(rintf(v[j].y / s), -8.f), 7.f);
        p.c[2] = (signed char)fminf(fmaxf(rintf(v[j].z / s), -8.f), 7.f);
        p.c[3] = (signed char)fminf(fmaxf(rintf(v[j].w / s), -8.f), 7.f);
        qr[tid + j * 256] = p.u;
    }
    if (tid == 0) sx[row] = s * (*wscale);     // fused output scale
}

// ---------------- Phase 4: int8 GEMM (256x256, BK=64, ring-4, reg-dbuf) ----
// A = qx (MxK row-major), B = qw (NxK row-major, i.e. B^T GEMM).
// 8 waves (2Mx4N), each computes 128x64 via 8x4 grid of 16x16x64 i8 MFMAs.
// LDS chunk swizzle (measured zero-conflict): chunk (row r, kgroup q) at byte
// offset r*64 + ((q+(r>>1))&3)*16; inverse applied on the global source so
// global_load_lds stays lane-linear. The swizzle slot ((fq+(r>>1))&3) is
// invariant in the fragment index -> all frag reads = one base VGPR +
// compile-time offset immediates.

// BODY(T): MFMA tile T from (CA,CB); read tile T+1 frags into (NA,NB);
// stage tile T+3. One counted vmcnt + s_barrier per tile.
#define GEMM_BODY(T, CA, CB, NA, NB)                                          \
    {                                                                         \
        if ((T) < 62) { asm volatile("s_waitcnt vmcnt(4)" ::: "memory"); }    \
        else          { asm volatile("s_waitcnt vmcnt(0)" ::: "memory"); }    \
        asm volatile("s_barrier" ::: "memory");                               \
        if ((T) < 63) {                                                       \
            const signed char* nxt = &lds[((T) + 1) & 3][0];                  \
            _Pragma("unroll")                                                 \
            for (int j_ = 0; j_ < 4; ++j_)                                    \
                NB[j_] = *(const v4i*)(nxt + offB0 + j_ * 1024);              \
            _Pragma("unroll")                                                 \
            for (int i_ = 0; i_ < 8; ++i_)                                    \
                NA[i_] = *(const v4i*)(nxt + offA0 + i_ * 1024);              \
        }                                                                     \
        if ((T) <= 60) {                                                      \
            signed char* sb = &lds[((T) + 3) & 3][0];                         \
            const long k3 = (long)((T) + 3) << 6;                             \
            gl_lds16(gA + k3,                 sb + oSA0);                     \
            gl_lds16(gA + 128 * K_DIM + k3,   sb + oSA1);                     \
            gl_lds16(gB + k3,                 sb + oSB0);                     \
            gl_lds16(gB + 128 * K_DIM + k3,   sb + oSB1);                     \
        }                                                                     \
        __builtin_amdgcn_s_setprio(1);                                        \
        _Pragma("unroll")                                                     \
        for (int i_ = 0; i_ < 8; ++i_)                                        \
            _Pragma("unroll")                                                 \
            for (int j_ = 0; j_ < 4; ++j_)                                    \
                acc[i_][j_] = __builtin_amdgcn_mfma_i32_16x16x64_i8(          \
                    CA[i_], CB[j_], acc[i_][j_], 0, 0, 0);                    \
        __builtin_amdgcn_s_setprio(0);                                        \
    }

__global__ __launch_bounds__(512, 2) void gemm_k(const signed char* __restrict__ qx,
                                                 const signed char* __restrict__ qw,
                                                 const float* __restrict__ sx,
                                                 float* __restrict__ out) {
    // ring of 4 buffers: [A 16 KB | B 16 KB] each
    __shared__ __align__(16) signed char lds[4][32768];

    const int tid  = threadIdx.x;
    const int lane = tid & 63;
    const int wave = tid >> 6;
    const int wm = wave >> 2;          // 0..1
    const int wn = wave & 3;           // 0..3

    // XCD-aware mapping: grid = 2048 linear (2048 % 8 == 0 -> bijective).
    const int bid = blockIdx.x;
    const int xcd = bid & 7;
    const int cid = bid >> 3;                           // 0..255
    const int mt  = (cid >> 1) & 31;                    // 32 m-tiles
    const int nt  = (xcd << 3) + ((cid >> 6) << 1) + (cid & 1);  // 64 n-tiles
    const int m0 = mt << 8;
    const int n0 = nt << 8;

    // ---- staging addresses (thread stages chunks {tid, tid+512} of A and B) --
    // chunk c: row r = c>>2, lds slot = c&3, global kgroup g = ((c&3)-((r>>1)&3))&3
    const int r = tid >> 2;                              // 0..127
    const int g = ((tid & 3) - ((tid >> 3) & 3)) & 3;    // inverse swizzle
    const signed char* gA = qx + (long)(m0 + r) * K_DIM + (g << 4);
    const signed char* gB = qw + (long)(n0 + r) * K_DIM + (g << 4);
    const int oSA0 = tid << 4;
    const int oSA1 = (tid << 4) + 8192;
    const int oSB0 = (tid << 4) + 16384;
    const int oSB1 = (tid << 4) + 24576;

    // ---- fragment bases: A[m=lane&15][k=(lane>>4)*16+j] ----
    // swizzle slot ((fq+(row>>1))&3) is invariant in frag idx and wave idx.
    const int fr = lane & 15;
    const int fq = lane >> 4;
    const int slot = ((fq + (fr >> 1)) & 3) << 4;
    const int offA0 = (wm * 128 + fr) * 64 + slot;            // frag i: +i*1024
    const int offB0 = 16384 + (wn * 64 + fr) * 64 + slot;     // frag j: +j*1024

    v4i acc[8][4];
#pragma unroll
    for (int i = 0; i < 8; ++i)
#pragma unroll
        for (int j = 0; j < 4; ++j) acc[i][j] = 0;

    // ---- prologue: stage tiles 0,1,2 (4 loads per tile, issue order defines
    // vmcnt groups), then pre-read tile 0's fragments ----
    gl_lds16(gA,                       &lds[0][oSA0]);
    gl_lds16(gA + 128 * K_DIM,         &lds[0][oSA1]);
    gl_lds16(gB,                       &lds[0][oSB0]);
    gl_lds16(gB + 128 * K_DIM,         &lds[0][oSB1]);
    gl_lds16(gA + 64,                  &lds[1][oSA0]);
    gl_lds16(gA + 128 * K_DIM + 64,    &lds[1][oSA1]);
    gl_lds16(gB + 64,                  &lds[1][oSB0]);
    gl_lds16(gB + 128 * K_DIM + 64,    &lds[1][oSB1]);
    gl_lds16(gA + 128,                 &lds[2][oSA0]);
    gl_lds16(gA + 128 * K_DIM + 128,   &lds[2][oSA1]);
    gl_lds16(gB + 128,                 &lds[2][oSB0]);
    gl_lds16(gB + 128 * K_DIM + 128,   &lds[2][oSB1]);

    asm volatile("s_waitcnt vmcnt(8)" ::: "memory");   // tile 0 landed
    asm volatile("s_barrier" ::: "memory");

    v4i a0[8], b0[4], a1[8], b1[4];
#pragma unroll
    for (int j = 0; j < 4; ++j) b0[j] = *(const v4i*)(&lds[0][0] + offB0 + j * 1024);
#pragma unroll
    for (int i = 0; i < 8; ++i) a0[i] = *(const v4i*)(&lds[0][0] + offA0 + i * 1024);

    // ---- main loop: 64 K-tiles, unrolled x2 for static reg-set parity ----
#pragma unroll 1
    for (int t = 0; t < 64; t += 2) {
        GEMM_BODY(t,     a0, b0, a1, b1);
        GEMM_BODY(t + 1, a1, b1, a0, b0);
    }

    // ---- epilogue: C/D layout col=lane&15, row=(lane>>4)*4+reg ----
#pragma unroll
    for (int i = 0; i < 8; ++i) {
        const int mrow = m0 + wm * 128 + i * 16 + fq * 4;
#pragma unroll
        for (int rr = 0; rr < 4; ++rr) {
            const int m = mrow + rr;
            const float sm = sx[m];
            float* orow = out + (long)m * N_DIM + n0 + wn * 64 + fr;
#pragma unroll
            for (int j = 0; j < 4; ++j)
                orow[j * 16] = (float)acc[i][j][rr] * sm;
        }
    }
}

extern "C" void kernel_launch(void* const* d_in, const int* in_sizes, int n_in,
                              void* d_out, int out_size, void* d_ws, size_t ws_size,
                              hipStream_t stream) {
    const float* x = (const float*)d_in[0];        // (4,2048,4096) fp32
    const float* w = (const float*)d_in[1];        // (16384,4096) fp32
    float* out = (float*)d_out;                    // (4,2048,16384) fp32
    char* ws = (char*)d_ws;

    // workspace layout (~100.7 MB total)
    double* part         = (double*)(ws);                        // 8 KB
    float*  wscale       = (float*)(ws + 8192);                  // 4 B
    float*  sx           = (float*)(ws + 16384);                 // 32 KB
    signed char* qx      = (signed char*)(ws + 65536);                    // 32 MB
    signed char* qw      = (signed char*)(ws + 65536 + (size_t)33554432); // 64 MB

    wabs_partial_k<<<1024, 256, 0, stream>>>(w, part);
    wscale_final_k<<<1, 256, 0, stream>>>(part, wscale);
    wquant_k<<<2048, 256, 0, stream>>>(w, qw, wscale);
    xquant_k<<<8192, 256, 0, stream>>>(x, qx, sx, wscale);
    gemm_k<<<2048, 512, 0, stream>>>(qx, qw, sx, out);
}